// Round 2
// baseline (717.609 us; speedup 1.0000x reference)
//
#include <hip/hip_runtime.h>

// LinearAttention (fp32 in/out, bf16 internal MFMA):
// x(8,64,64,256) f32, w_qkv(256,1536) f32, gn_scale/bias(512) f32,
// w_out(512,256) f32, b_out(256) f32 -> out(8,64,64,256) f32
// B=8, N=4096 tokens/batch, HEADS=8, DH=64, HID=512, DIM=256.

typedef unsigned short ushort_t;
typedef __attribute__((ext_vector_type(8))) short short8;
typedef __attribute__((ext_vector_type(4))) float floatx4;

__device__ __forceinline__ float b2f(ushort_t u) {
  unsigned int i = ((unsigned int)u) << 16;
  float f;
  __builtin_memcpy(&f, &i, 4);
  return f;
}
__device__ __forceinline__ ushort_t f2b(float f) {
  unsigned int i;
  __builtin_memcpy(&i, &f, 4);
  unsigned int r = (i + 0x7FFFu + ((i >> 16) & 1u)) >> 16;
  return (ushort_t)r;
}

// ---------------------------------------------------------------------------
// Cast fp32 -> bf16, contiguous. 4 elements/thread.
// ---------------------------------------------------------------------------
__global__ __launch_bounds__(256) void cast_f32_bf16(
    const float* __restrict__ in, ushort_t* __restrict__ out) {
  long i = ((long)blockIdx.x * 256 + threadIdx.x) * 4;
  float4 v = *(const float4*)(in + i);
  ushort4 o;
  o.x = f2b(v.x);
  o.y = f2b(v.y);
  o.z = f2b(v.z);
  o.w = f2b(v.w);
  *(ushort4*)(out + i) = o;
}

// ---------------------------------------------------------------------------
// Transpose fp32 R x C -> bf16 C x R. R,C multiples of 32.
// ---------------------------------------------------------------------------
__global__ __launch_bounds__(256) void transpose_f32_bf16(
    const float* __restrict__ in, ushort_t* __restrict__ out, int R, int C) {
  __shared__ ushort_t t[32][33];
  int c0 = blockIdx.x * 32, r0 = blockIdx.y * 32;
  int tx = threadIdx.x & 31, ty = threadIdx.x >> 5;  // ty 0..7
  for (int i = 0; i < 32; i += 8)
    t[ty + i][tx] = f2b(in[(long)(r0 + ty + i) * C + c0 + tx]);
  __syncthreads();
  for (int i = 0; i < 32; i += 8)
    out[(long)(c0 + ty + i) * R + r0 + tx] = t[tx][ty + i];
}

// ---------------------------------------------------------------------------
// MFMA GEMM: C[M,F] = A[M,K] @ Bt[F,K]^T  (bf16 in, OT out, fp32 acc)
// M%128==0, F%128==0, K%32==0. Optional fp32 bias[F] added in epilogue.
// Block = 256 thr = 4 waves in 2x2; wave does 64x64 via 4x4 mfma 16x16x32.
// ---------------------------------------------------------------------------
template <typename OT>
__global__ __launch_bounds__(256) void gemm_bt(
    const ushort_t* __restrict__ A, const ushort_t* __restrict__ Bt,
    OT* __restrict__ C, int M, int K, int F, const float* __restrict__ bias) {
  __shared__ __align__(16) ushort_t As[128][32];
  __shared__ __align__(16) ushort_t Bs[128][32];
  int tid = threadIdx.x;
  long m0 = (long)blockIdx.x * 128;
  long f0 = (long)blockIdx.y * 128;
  int wv = tid >> 6, lane = tid & 63;
  int wm = wv & 1, wf = wv >> 1;
  int l15 = lane & 15, quad = lane >> 4;

  floatx4 acc[4][4];
  floatx4 zero = {0.f, 0.f, 0.f, 0.f};
  for (int i = 0; i < 4; i++)
    for (int j = 0; j < 4; j++) acc[i][j] = zero;

  for (int k0 = 0; k0 < K; k0 += 32) {
    __syncthreads();
    // stage 128x32 of A and Bt, 16B per thread per round, 2 rounds each
    for (int r = 0; r < 2; ++r) {
      int chunk = r * 256 + tid;  // 0..511
      int row = chunk >> 2;       // 0..127
      int kc = chunk & 3;         // 0..3 (8 bf16 each)
      *(uint4*)(&As[row][kc * 8]) =
          *(const uint4*)(A + (m0 + row) * (long)K + k0 + kc * 8);
      *(uint4*)(&Bs[row][kc * 8]) =
          *(const uint4*)(Bt + (f0 + row) * (long)K + k0 + kc * 8);
    }
    __syncthreads();
    short8 af[4], bfr[4];
#pragma unroll
    for (int mt = 0; mt < 4; mt++)
      af[mt] = *(const short8*)(&As[wm * 64 + mt * 16 + l15][quad * 8]);
#pragma unroll
    for (int ft = 0; ft < 4; ft++)
      bfr[ft] = *(const short8*)(&Bs[wf * 64 + ft * 16 + l15][quad * 8]);
#pragma unroll
    for (int mt = 0; mt < 4; mt++)
#pragma unroll
      for (int ft = 0; ft < 4; ft++)
        acc[mt][ft] = __builtin_amdgcn_mfma_f32_16x16x32_bf16(
            af[mt], bfr[ft], acc[mt][ft], 0, 0, 0);
  }

  // epilogue: D[row = quad*4 + r][col = l15] within each 16x16 tile
#pragma unroll
  for (int mt = 0; mt < 4; mt++)
#pragma unroll
    for (int ft = 0; ft < 4; ft++) {
      long col = f0 + wf * 64 + ft * 16 + l15;
      float bv = bias ? bias[col] : 0.f;
#pragma unroll
      for (int r = 0; r < 4; r++) {
        long row = m0 + wm * 64 + mt * 16 + quad * 4 + r;
        float val = acc[mt][ft][r] + bv;
        if constexpr (sizeof(OT) == 2)
          C[row * F + col] = (OT)f2b(val);
        else
          C[row * F + col] = (OT)val;
      }
    }
}

// ---------------------------------------------------------------------------
// k softmax stats over n=4096 per (b,h,d). Block per (b,h), lane = d.
// qkv layout: [b*4096+n][1536], k at offset 512 + h*64 + d.
// ---------------------------------------------------------------------------
__global__ __launch_bounds__(256) void kstats_kernel(
    const ushort_t* __restrict__ qkv, float* __restrict__ kmax,
    float* __restrict__ kinv) {
  int bh = blockIdx.x;  // 64
  int b = bh >> 3, h = bh & 7;
  int wv = threadIdx.x >> 6, lane = threadIdx.x & 63;
  const ushort_t* base = qkv + ((long)b * 4096) * 1536 + 512 + h * 64 + lane;
  float m = -1e30f, s = 0.f;
  for (int n = wv * 1024; n < wv * 1024 + 1024; ++n) {
    float v = b2f(base[(long)n * 1536]);
    if (v > m) {
      s = s * __expf(m - v) + 1.0f;
      m = v;
    } else {
      s += __expf(v - m);
    }
  }
  __shared__ float sm[4][64], ss[4][64];
  sm[wv][lane] = m;
  ss[wv][lane] = s;
  __syncthreads();
  if (wv == 0) {
    float M = sm[0][lane], S = ss[0][lane];
    for (int w2 = 1; w2 < 4; w2++) {
      float m2 = sm[w2][lane], s2 = ss[w2][lane];
      float nm = fmaxf(M, m2);
      S = S * __expf(M - nm) + s2 * __expf(m2 - nm);
      M = nm;
    }
    kmax[bh * 64 + lane] = M;
    kinv[bh * 64 + lane] = 1.0f / S;
  }
}

// ---------------------------------------------------------------------------
// context[bh][d][e] += sum_n exp(k[d,n]-kmax[d])*kinv[d] * v[e,n]
// Grid (64 bh, 16 n-chunks of 256). fp32 atomic accumulate into zeroed ctx.
// ---------------------------------------------------------------------------
__global__ __launch_bounds__(256) void ctx_kernel(
    const ushort_t* __restrict__ qkv, const float* __restrict__ kmax,
    const float* __restrict__ kinv, float* __restrict__ ctx) {
  int bh = blockIdx.x;
  int chunk = blockIdx.y;
  int b = bh >> 3, h = bh & 7;
  int tid = threadIdx.x;
  __shared__ float pk[64][65];
  __shared__ float pv[64][65];
  int dl = tid & 63;  // loading role: d (and e) index
  int nl = tid >> 6;  // 0..3
  float km = kmax[bh * 64 + dl], ki = kinv[bh * 64 + dl];
  int td = tid & 15, te = tid >> 4;
  float acc[4][4] = {};
  long rowbase = (long)b * 4096 + chunk * 256;
  for (int t = 0; t < 4; ++t) {  // 4 tiles of 64 tokens
    __syncthreads();
    for (int r = 0; r < 16; ++r) {
      int n = t * 64 + r * 4 + nl;
      const ushort_t* p = qkv + (rowbase + n) * 1536 + h * 64 + dl;
      pk[dl][r * 4 + nl] = __expf(b2f(p[512]) - km) * ki;
      pv[dl][r * 4 + nl] = b2f(p[1024]);
    }
    __syncthreads();
    for (int n = 0; n < 64; ++n) {
      float kd[4], ve[4];
#pragma unroll
      for (int i = 0; i < 4; i++) kd[i] = pk[td * 4 + i][n];
#pragma unroll
      for (int j = 0; j < 4; j++) ve[j] = pv[te * 4 + j][n];
#pragma unroll
      for (int i = 0; i < 4; i++)
#pragma unroll
        for (int j = 0; j < 4; j++) acc[i][j] += kd[i] * ve[j];
    }
  }
  float* cbase = ctx + (long)bh * 4096;
#pragma unroll
  for (int i = 0; i < 4; i++)
#pragma unroll
    for (int j = 0; j < 4; j++)
      atomicAdd(&cbase[(td * 4 + i) * 64 + te * 4 + j], acc[i][j]);
}

// ---------------------------------------------------------------------------
// out[b,n,h*64+e] = sum_d ctx[bh][d][e] * softmax_d(q[:,n]) * 0.125
// Also accumulates GN sum / sumsq per batch. Grid (64 bh, 8 chunks of 512).
// Wave per token (4 tokens in flight per block). lane plays d then e.
// ---------------------------------------------------------------------------
__global__ __launch_bounds__(256) void attn_out_kernel(
    const ushort_t* __restrict__ qkv, const float* __restrict__ ctx,
    float* __restrict__ oa, float* __restrict__ gstats) {
  int bh = blockIdx.x;
  int chunk = blockIdx.y;
  int b = bh >> 3, h = bh & 7;
  int wv = threadIdx.x >> 6, lane = threadIdx.x & 63;
  float creg[64];  // ctx[d][lane] for all d
  const float* cb = ctx + (long)bh * 4096 + lane;
#pragma unroll
  for (int d = 0; d < 64; ++d) creg[d] = cb[d * 64];
  __shared__ float qs[4][64];
  float lsum = 0.f, lss = 0.f;
  for (int ti = 0; ti < 128; ++ti) {
    int n = chunk * 512 + ti * 4 + wv;
    long row = (long)b * 4096 + n;
    float qv = b2f(qkv[row * 1536 + h * 64 + lane]);
    float m = qv;
    for (int o = 32; o > 0; o >>= 1) m = fmaxf(m, __shfl_xor(m, o));
    float e = __expf(qv - m);
    float s = e;
    for (int o = 32; o > 0; o >>= 1) s += __shfl_xor(s, o);
    float q = e / s * 0.125f;  // * DH^-0.5
    qs[wv][lane] = q;
    float o = 0.f;
#pragma unroll
    for (int d = 0; d < 64; ++d) o += qs[wv][d] * creg[d];
    oa[row * 512 + h * 64 + lane] = o;
    lsum += o;
    lss += o * o;
  }
  for (int o = 32; o > 0; o >>= 1) {
    lsum += __shfl_xor(lsum, o);
    lss += __shfl_xor(lss, o);
  }
  __shared__ float red[4][2];
  if (lane == 0) {
    red[wv][0] = lsum;
    red[wv][1] = lss;
  }
  __syncthreads();
  if (threadIdx.x == 0) {
    float a = 0.f, c = 0.f;
    for (int w2 = 0; w2 < 4; w2++) {
      a += red[w2][0];
      c += red[w2][1];
    }
    atomicAdd(&gstats[b * 2], a);
    atomicAdd(&gstats[b * 2 + 1], c);
  }
}

// ---------------------------------------------------------------------------
// Finalize: mu/rsqrt per batch; bias2[c] = sum_f gn_bias[f]*w_out[f,c]+b_out[c]
// One block of 256. All params fp32.
// ---------------------------------------------------------------------------
__global__ __launch_bounds__(256) void finalize_kernel(
    const float* __restrict__ gstats, const float* __restrict__ gn_bias,
    const float* __restrict__ w_out, const float* __restrict__ b_out,
    float* __restrict__ murs, float* __restrict__ bias2) {
  int tid = threadIdx.x;
  if (tid < 8) {
    float cnt = 4096.f * 512.f;
    float mu = gstats[tid * 2] / cnt;
    float var = gstats[tid * 2 + 1] / cnt - mu * mu;
    murs[tid * 2] = mu;
    murs[tid * 2 + 1] = rsqrtf(var + 1e-5f);
  }
  float a = b_out[tid];
  for (int f = 0; f < 512; ++f) a += gn_bias[f] * w_out[f * 256 + tid];
  bias2[tid] = a;
}

// ---------------------------------------------------------------------------
// Normalize + cast: A2[m,f] = (oa[m,f]-mu[b]) * rs[b] * gn_scale[f]  (bf16)
// 4 elements per thread.
// ---------------------------------------------------------------------------
__global__ __launch_bounds__(256) void norm_cast_kernel(
    const float* __restrict__ oa, const float* __restrict__ murs,
    const float* __restrict__ gn_scale, ushort_t* __restrict__ A2) {
  long idx = ((long)blockIdx.x * 256 + threadIdx.x) * 4;
  int b = (int)(idx >> 21);  // 4096*512 elements per batch
  float mu = murs[b * 2], rs = murs[b * 2 + 1];
  float4 v = *(const float4*)(oa + idx);
  int f = (int)(idx & 511);
  ushort4 o;
  o.x = f2b((v.x - mu) * rs * gn_scale[f + 0]);
  o.y = f2b((v.y - mu) * rs * gn_scale[f + 1]);
  o.z = f2b((v.z - mu) * rs * gn_scale[f + 2]);
  o.w = f2b((v.w - mu) * rs * gn_scale[f + 3]);
  *(ushort4*)(A2 + idx) = o;
}

// ---------------------------------------------------------------------------
extern "C" void kernel_launch(void* const* d_in, const int* in_sizes, int n_in,
                              void* d_out, int out_size, void* d_ws,
                              size_t ws_size, hipStream_t stream) {
  const float* x = (const float*)d_in[0];         // 8*64*64*256 f32
  const float* w_qkv = (const float*)d_in[1];     // 256*1536 f32
  const float* gn_scale = (const float*)d_in[2];  // 512 f32
  const float* gn_bias = (const float*)d_in[3];   // 512 f32
  const float* w_out = (const float*)d_in[4];     // 512*256 f32
  const float* b_out = (const float*)d_in[5];     // 256 f32
  float* out = (float*)d_out;                     // 8*64*64*256 f32

  char* w = (char*)d_ws;
  ushort_t* qkv = (ushort_t*)(w + 0);            // 100663296 B (32768x1536 bf16)
  float* oa = (float*)(w + 100663296);           // 67108864 B (32768x512 f32)
  ushort_t* xb = (ushort_t*)(w + 167772160);     // 16777216 B (32768x256 bf16)
  ushort_t* wqkvT = (ushort_t*)(w + 184549376);  // 786432 B (1536x256 bf16)
  ushort_t* woutT = (ushort_t*)(w + 185335808);  // 262144 B (256x512 bf16)
  float* kmax = (float*)(w + 185597952);         // 16384 B
  float* kinv = (float*)(w + 185614336);         // 16384 B
  float* ctx = (float*)(w + 185630720);          // 1048576 B (64*64*64 f32)
  float* gstats = (float*)(w + 186679296);       // 64 B (8 x {sum,ss})
  float* murs = (float*)(w + 186679360);         // 64 B
  float* bias2 = (float*)(w + 186679424);        // 1024 B
  ushort_t* A2 = qkv;  // reuse qkv region (dead after attn_out)

  // zero ctx + gstats (contiguous)
  hipMemsetAsync(ctx, 0, 1048576 + 64, stream);

  // cast x -> bf16
  cast_f32_bf16<<<8388608 / 4 / 256, 256, 0, stream>>>(x, xb);
  // transposes+cast: w_qkv (256x1536) -> (1536x256); w_out (512x256)->(256x512)
  transpose_f32_bf16<<<dim3(1536 / 32, 256 / 32), 256, 0, stream>>>(
      w_qkv, wqkvT, 256, 1536);
  transpose_f32_bf16<<<dim3(256 / 32, 512 / 32), 256, 0, stream>>>(
      w_out, woutT, 512, 256);
  // QKV GEMM: (32768x256)@(256x1536) -> bf16 qkv
  gemm_bt<ushort_t><<<dim3(32768 / 128, 1536 / 128), 256, 0, stream>>>(
      xb, wqkvT, qkv, 32768, 256, 1536, nullptr);
  // k softmax stats
  kstats_kernel<<<64, 256, 0, stream>>>(qkv, kmax, kinv);
  // context
  ctx_kernel<<<dim3(64, 16), 256, 0, stream>>>(qkv, kmax, kinv, ctx);
  // attention out + GN stats
  attn_out_kernel<<<dim3(64, 8), 256, 0, stream>>>(qkv, ctx, oa, gstats);
  // finalize mu/rs + folded bias
  finalize_kernel<<<1, 256, 0, stream>>>(gstats, gn_bias, w_out, b_out, murs,
                                         bias2);
  // normalize + cast to bf16
  norm_cast_kernel<<<(32768 * 512 / 4) / 256, 256, 0, stream>>>(oa, murs,
                                                                gn_scale, A2);
  // final GEMM: (32768x512)@(512x256) + bias2 -> fp32 out
  gemm_bt<float><<<dim3(32768 / 128, 256 / 128), 256, 0, stream>>>(
      A2, woutT, out, 32768, 512, 256, bias2);
}

// Round 3
// 437.990 us; speedup vs baseline: 1.6384x; 1.6384x over previous
//
#include <hip/hip_runtime.h>

// LinearAttention (fp32 in/out, bf16 internal MFMA):
// x(8,64,64,256) f32, w_qkv(256,1536) f32, gn_scale/bias(512) f32,
// w_out(512,256) f32, b_out(256) f32 -> out(8,64,64,256) f32
// B=8, N=4096 tokens/batch, HEADS=8, DH=64, HID=512, DIM=256.

typedef unsigned short ushort_t;
typedef __attribute__((ext_vector_type(8))) short short8;
typedef __attribute__((ext_vector_type(4))) float floatx4;

__device__ __forceinline__ float b2f(ushort_t u) {
  unsigned int i = ((unsigned int)u) << 16;
  float f;
  __builtin_memcpy(&f, &i, 4);
  return f;
}
__device__ __forceinline__ ushort_t f2b(float f) {
  unsigned int i;
  __builtin_memcpy(&i, &f, 4);
  unsigned int r = (i + 0x7FFFu + ((i >> 16) & 1u)) >> 16;
  return (ushort_t)r;
}

// ---------------------------------------------------------------------------
// Cast fp32 -> bf16, contiguous. 4 elements/thread.
// ---------------------------------------------------------------------------
__global__ __launch_bounds__(256) void cast_f32_bf16(
    const float* __restrict__ in, ushort_t* __restrict__ out) {
  long i = ((long)blockIdx.x * 256 + threadIdx.x) * 4;
  float4 v = *(const float4*)(in + i);
  ushort4 o;
  o.x = f2b(v.x);
  o.y = f2b(v.y);
  o.z = f2b(v.z);
  o.w = f2b(v.w);
  *(ushort4*)(out + i) = o;
}

// ---------------------------------------------------------------------------
// Transpose fp32 R x C -> bf16 C x R. R,C multiples of 32.
// ---------------------------------------------------------------------------
__global__ __launch_bounds__(256) void transpose_f32_bf16(
    const float* __restrict__ in, ushort_t* __restrict__ out, int R, int C) {
  __shared__ ushort_t t[32][33];
  int c0 = blockIdx.x * 32, r0 = blockIdx.y * 32;
  int tx = threadIdx.x & 31, ty = threadIdx.x >> 5;  // ty 0..7
  for (int i = 0; i < 32; i += 8)
    t[ty + i][tx] = f2b(in[(long)(r0 + ty + i) * C + c0 + tx]);
  __syncthreads();
  for (int i = 0; i < 32; i += 8)
    out[(long)(c0 + ty + i) * R + r0 + tx] = t[tx][ty + i];
}

// ---------------------------------------------------------------------------
// MFMA GEMM: C[M,F] = A[M,K] @ Bt[F,K]^T  (bf16 in, OT out, fp32 acc)
// M%128==0, F%128==0, K%32==0. Optional fp32 bias[F] added in epilogue.
// Block = 256 thr = 4 waves in 2x2; wave does 64x64 via 4x4 mfma 16x16x32.
// ---------------------------------------------------------------------------
template <typename OT>
__global__ __launch_bounds__(256) void gemm_bt(
    const ushort_t* __restrict__ A, const ushort_t* __restrict__ Bt,
    OT* __restrict__ C, int M, int K, int F, const float* __restrict__ bias) {
  __shared__ __align__(16) ushort_t As[128][32];
  __shared__ __align__(16) ushort_t Bs[128][32];
  int tid = threadIdx.x;
  long m0 = (long)blockIdx.x * 128;
  long f0 = (long)blockIdx.y * 128;
  int wv = tid >> 6, lane = tid & 63;
  int wm = wv & 1, wf = wv >> 1;
  int l15 = lane & 15, quad = lane >> 4;

  floatx4 acc[4][4];
  floatx4 zero = {0.f, 0.f, 0.f, 0.f};
  for (int i = 0; i < 4; i++)
    for (int j = 0; j < 4; j++) acc[i][j] = zero;

  for (int k0 = 0; k0 < K; k0 += 32) {
    __syncthreads();
    // stage 128x32 of A and Bt, 16B per thread per round, 2 rounds each
    for (int r = 0; r < 2; ++r) {
      int chunk = r * 256 + tid;  // 0..511
      int row = chunk >> 2;       // 0..127
      int kc = chunk & 3;         // 0..3 (8 bf16 each)
      *(uint4*)(&As[row][kc * 8]) =
          *(const uint4*)(A + (m0 + row) * (long)K + k0 + kc * 8);
      *(uint4*)(&Bs[row][kc * 8]) =
          *(const uint4*)(Bt + (f0 + row) * (long)K + k0 + kc * 8);
    }
    __syncthreads();
    short8 af[4], bfr[4];
#pragma unroll
    for (int mt = 0; mt < 4; mt++)
      af[mt] = *(const short8*)(&As[wm * 64 + mt * 16 + l15][quad * 8]);
#pragma unroll
    for (int ft = 0; ft < 4; ft++)
      bfr[ft] = *(const short8*)(&Bs[wf * 64 + ft * 16 + l15][quad * 8]);
#pragma unroll
    for (int mt = 0; mt < 4; mt++)
#pragma unroll
      for (int ft = 0; ft < 4; ft++)
        acc[mt][ft] = __builtin_amdgcn_mfma_f32_16x16x32_bf16(
            af[mt], bfr[ft], acc[mt][ft], 0, 0, 0);
  }

  // epilogue: D[row = quad*4 + r][col = l15] within each 16x16 tile
#pragma unroll
  for (int mt = 0; mt < 4; mt++)
#pragma unroll
    for (int ft = 0; ft < 4; ft++) {
      long col = f0 + wf * 64 + ft * 16 + l15;
      float bv = bias ? bias[col] : 0.f;
#pragma unroll
      for (int r = 0; r < 4; r++) {
        long row = m0 + wm * 64 + mt * 16 + quad * 4 + r;
        float val = acc[mt][ft][r] + bv;
        if constexpr (sizeof(OT) == 2)
          C[row * F + col] = (OT)f2b(val);
        else
          C[row * F + col] = (OT)val;
      }
    }
}

// ---------------------------------------------------------------------------
// k softmax partial stats. Grid (64 bh, 16 chunks of 256 tokens), block 256.
// Lane = d; each wave online-reduces 64 tokens; waves combine via LDS.
// Writes per-(bh,chunk,d) partial (max, sumexp).
// ---------------------------------------------------------------------------
__global__ __launch_bounds__(256) void kpart_kernel(
    const ushort_t* __restrict__ qkv, float* __restrict__ kpM,
    float* __restrict__ kpS) {
  int bh = blockIdx.x, chunk = blockIdx.y;
  int b = bh >> 3, h = bh & 7;
  int wv = threadIdx.x >> 6, lane = threadIdx.x & 63;
  const ushort_t* base = qkv +
      ((long)b * 4096 + chunk * 256 + wv * 64) * 1536 + 512 + h * 64 + lane;
  float m = -1e30f, s = 0.f;
  for (int i = 0; i < 64; ++i) {
    float v = b2f(base[(long)i * 1536]);
    if (v > m) {
      s = s * __expf(m - v) + 1.0f;
      m = v;
    } else {
      s += __expf(v - m);
    }
  }
  __shared__ float sm[4][64], ss[4][64];
  sm[wv][lane] = m;
  ss[wv][lane] = s;
  __syncthreads();
  if (wv == 0) {
    float M = sm[0][lane], S = ss[0][lane];
    for (int w2 = 1; w2 < 4; w2++) {
      float m2 = sm[w2][lane], s2 = ss[w2][lane];
      float nm = fmaxf(M, m2);
      S = S * __expf(M - nm) + s2 * __expf(m2 - nm);
      M = nm;
    }
    int idx = (bh * 16 + chunk) * 64 + lane;
    kpM[idx] = M;
    kpS[idx] = S;
  }
}

// ---------------------------------------------------------------------------
// Combine 16 partial (m,s) per (bh,d) -> kmax, kinv. Grid 64, block 64.
// ---------------------------------------------------------------------------
__global__ __launch_bounds__(64) void kcombine_kernel(
    const float* __restrict__ kpM, const float* __restrict__ kpS,
    float* __restrict__ kmax, float* __restrict__ kinv) {
  int bh = blockIdx.x, lane = threadIdx.x;
  float M = -1e30f, S = 0.f;
  for (int c = 0; c < 16; ++c) {
    float m2 = kpM[(bh * 16 + c) * 64 + lane];
    float s2 = kpS[(bh * 16 + c) * 64 + lane];
    float nm = fmaxf(M, m2);
    S = S * __expf(M - nm) + s2 * __expf(m2 - nm);
    M = nm;
  }
  kmax[bh * 64 + lane] = M;
  kinv[bh * 64 + lane] = 1.0f / S;
}

// ---------------------------------------------------------------------------
// context[bh][d][e] += sum_n exp(k[d,n]-kmax[d])*kinv[d] * v[e,n]
// Grid (64 bh, 16 n-chunks of 256). fp32 atomic accumulate into zeroed ctx.
// ---------------------------------------------------------------------------
__global__ __launch_bounds__(256) void ctx_kernel(
    const ushort_t* __restrict__ qkv, const float* __restrict__ kmax,
    const float* __restrict__ kinv, float* __restrict__ ctx) {
  int bh = blockIdx.x;
  int chunk = blockIdx.y;
  int b = bh >> 3, h = bh & 7;
  int tid = threadIdx.x;
  __shared__ float pk[64][65];
  __shared__ float pv[64][65];
  int dl = tid & 63;  // loading role: d (and e) index
  int nl = tid >> 6;  // 0..3
  float km = kmax[bh * 64 + dl], ki = kinv[bh * 64 + dl];
  int td = tid & 15, te = tid >> 4;
  float acc[4][4] = {};
  long rowbase = (long)b * 4096 + chunk * 256;
  for (int t = 0; t < 4; ++t) {  // 4 tiles of 64 tokens
    __syncthreads();
    for (int r = 0; r < 16; ++r) {
      int n = t * 64 + r * 4 + nl;
      const ushort_t* p = qkv + (rowbase + n) * 1536 + h * 64 + dl;
      pk[dl][r * 4 + nl] = __expf(b2f(p[512]) - km) * ki;
      pv[dl][r * 4 + nl] = b2f(p[1024]);
    }
    __syncthreads();
    for (int n = 0; n < 64; ++n) {
      float kd[4], ve[4];
#pragma unroll
      for (int i = 0; i < 4; i++) kd[i] = pk[td * 4 + i][n];
#pragma unroll
      for (int j = 0; j < 4; j++) ve[j] = pv[te * 4 + j][n];
#pragma unroll
      for (int i = 0; i < 4; i++)
#pragma unroll
        for (int j = 0; j < 4; j++) acc[i][j] += kd[i] * ve[j];
    }
  }
  float* cbase = ctx + (long)bh * 4096;
#pragma unroll
  for (int i = 0; i < 4; i++)
#pragma unroll
    for (int j = 0; j < 4; j++)
      atomicAdd(&cbase[(td * 4 + i) * 64 + te * 4 + j], acc[i][j]);
}

// ---------------------------------------------------------------------------
// out[b,n,h*64+e] = sum_d ctx[bh][d][e] * softmax_d(q[:,n]) * 0.125
// Also accumulates GN sum / sumsq per batch. Grid (64 bh, 8 chunks of 512).
// Wave per token (4 tokens in flight per block). lane plays d then e.
// ---------------------------------------------------------------------------
__global__ __launch_bounds__(256) void attn_out_kernel(
    const ushort_t* __restrict__ qkv, const float* __restrict__ ctx,
    float* __restrict__ oa, float* __restrict__ gstats) {
  int bh = blockIdx.x;
  int chunk = blockIdx.y;
  int b = bh >> 3, h = bh & 7;
  int wv = threadIdx.x >> 6, lane = threadIdx.x & 63;
  float creg[64];  // ctx[d][lane] for all d
  const float* cb = ctx + (long)bh * 4096 + lane;
#pragma unroll
  for (int d = 0; d < 64; ++d) creg[d] = cb[d * 64];
  __shared__ float qs[4][64];
  float lsum = 0.f, lss = 0.f;
  for (int ti = 0; ti < 128; ++ti) {
    int n = chunk * 512 + ti * 4 + wv;
    long row = (long)b * 4096 + n;
    float qv = b2f(qkv[row * 1536 + h * 64 + lane]);
    float m = qv;
    for (int o = 32; o > 0; o >>= 1) m = fmaxf(m, __shfl_xor(m, o));
    float e = __expf(qv - m);
    float s = e;
    for (int o = 32; o > 0; o >>= 1) s += __shfl_xor(s, o);
    float q = e / s * 0.125f;  // * DH^-0.5
    qs[wv][lane] = q;
    float o = 0.f;
#pragma unroll
    for (int d = 0; d < 64; ++d) o += qs[wv][d] * creg[d];
    oa[row * 512 + h * 64 + lane] = o;
    lsum += o;
    lss += o * o;
  }
  for (int o = 32; o > 0; o >>= 1) {
    lsum += __shfl_xor(lsum, o);
    lss += __shfl_xor(lss, o);
  }
  __shared__ float red[4][2];
  if (lane == 0) {
    red[wv][0] = lsum;
    red[wv][1] = lss;
  }
  __syncthreads();
  if (threadIdx.x == 0) {
    float a = 0.f, c = 0.f;
    for (int w2 = 0; w2 < 4; w2++) {
      a += red[w2][0];
      c += red[w2][1];
    }
    atomicAdd(&gstats[b * 2], a);
    atomicAdd(&gstats[b * 2 + 1], c);
  }
}

// ---------------------------------------------------------------------------
// Finalize: mu/rsqrt per batch; bias2[c] = sum_f gn_bias[f]*w_out[f,c]+b_out[c]
// One block of 256. All params fp32.
// ---------------------------------------------------------------------------
__global__ __launch_bounds__(256) void finalize_kernel(
    const float* __restrict__ gstats, const float* __restrict__ gn_bias,
    const float* __restrict__ w_out, const float* __restrict__ b_out,
    float* __restrict__ murs, float* __restrict__ bias2) {
  int tid = threadIdx.x;
  if (tid < 8) {
    float cnt = 4096.f * 512.f;
    float mu = gstats[tid * 2] / cnt;
    float var = gstats[tid * 2 + 1] / cnt - mu * mu;
    murs[tid * 2] = mu;
    murs[tid * 2 + 1] = rsqrtf(var + 1e-5f);
  }
  float a = b_out[tid];
  for (int f = 0; f < 512; ++f) a += gn_bias[f] * w_out[f * 256 + tid];
  bias2[tid] = a;
}

// ---------------------------------------------------------------------------
// Normalize + cast: A2[m,f] = (oa[m,f]-mu[b]) * rs[b] * gn_scale[f]  (bf16)
// 4 elements per thread.
// ---------------------------------------------------------------------------
__global__ __launch_bounds__(256) void norm_cast_kernel(
    const float* __restrict__ oa, const float* __restrict__ murs,
    const float* __restrict__ gn_scale, ushort_t* __restrict__ A2) {
  long idx = ((long)blockIdx.x * 256 + threadIdx.x) * 4;
  int b = (int)(idx >> 21);  // 4096*512 elements per batch
  float mu = murs[b * 2], rs = murs[b * 2 + 1];
  float4 v = *(const float4*)(oa + idx);
  int f = (int)(idx & 511);
  ushort4 o;
  o.x = f2b((v.x - mu) * rs * gn_scale[f + 0]);
  o.y = f2b((v.y - mu) * rs * gn_scale[f + 1]);
  o.z = f2b((v.z - mu) * rs * gn_scale[f + 2]);
  o.w = f2b((v.w - mu) * rs * gn_scale[f + 3]);
  *(ushort4*)(A2 + idx) = o;
}

// ---------------------------------------------------------------------------
extern "C" void kernel_launch(void* const* d_in, const int* in_sizes, int n_in,
                              void* d_out, int out_size, void* d_ws,
                              size_t ws_size, hipStream_t stream) {
  const float* x = (const float*)d_in[0];         // 8*64*64*256 f32
  const float* w_qkv = (const float*)d_in[1];     // 256*1536 f32
  const float* gn_scale = (const float*)d_in[2];  // 512 f32
  const float* gn_bias = (const float*)d_in[3];   // 512 f32
  const float* w_out = (const float*)d_in[4];     // 512*256 f32
  const float* b_out = (const float*)d_in[5];     // 256 f32
  float* out = (float*)d_out;                     // 8*64*64*256 f32

  char* w = (char*)d_ws;
  ushort_t* qkv = (ushort_t*)(w + 0);            // 100663296 B (32768x1536 bf16)
  float* oa = (float*)(w + 100663296);           // 67108864 B (32768x512 f32)
  ushort_t* xb = (ushort_t*)(w + 167772160);     // 16777216 B (32768x256 bf16)
  ushort_t* wqkvT = (ushort_t*)(w + 184549376);  // 786432 B (1536x256 bf16)
  ushort_t* woutT = (ushort_t*)(w + 185335808);  // 262144 B (256x512 bf16)
  float* kmax = (float*)(w + 185597952);         // 16384 B
  float* kinv = (float*)(w + 185614336);         // 16384 B
  float* ctx = (float*)(w + 185630720);          // 1048576 B (64*64*64 f32)
  float* gstats = (float*)(w + 186679296);       // 64 B (8 x {sum,ss})
  float* murs = (float*)(w + 186679360);         // 64 B
  float* bias2 = (float*)(w + 186679424);        // 1024 B
  float* kpM = (float*)(w + 186680448);          // 262144 B (64*16*64 f32)
  float* kpS = (float*)(w + 186942592);          // 262144 B
  ushort_t* A2 = qkv;  // reuse qkv region (dead after attn_out)

  // zero ctx + gstats (contiguous)
  hipMemsetAsync(ctx, 0, 1048576 + 64, stream);

  // cast x -> bf16
  cast_f32_bf16<<<8388608 / 4 / 256, 256, 0, stream>>>(x, xb);
  // transposes+cast: w_qkv (256x1536) -> (1536x256); w_out (512x256)->(256x512)
  transpose_f32_bf16<<<dim3(1536 / 32, 256 / 32), 256, 0, stream>>>(
      w_qkv, wqkvT, 256, 1536);
  transpose_f32_bf16<<<dim3(256 / 32, 512 / 32), 256, 0, stream>>>(
      w_out, woutT, 512, 256);
  // QKV GEMM: (32768x256)@(256x1536) -> bf16 qkv
  gemm_bt<ushort_t><<<dim3(32768 / 128, 1536 / 128), 256, 0, stream>>>(
      xb, wqkvT, qkv, 32768, 256, 1536, nullptr);
  // k softmax stats: two-level reduction (1024 blocks, then 64)
  kpart_kernel<<<dim3(64, 16), 256, 0, stream>>>(qkv, kpM, kpS);
  kcombine_kernel<<<64, 64, 0, stream>>>(kpM, kpS, kmax, kinv);
  // context
  ctx_kernel<<<dim3(64, 16), 256, 0, stream>>>(qkv, kmax, kinv, ctx);
  // attention out + GN stats
  attn_out_kernel<<<dim3(64, 8), 256, 0, stream>>>(qkv, ctx, oa, gstats);
  // finalize mu/rs + folded bias
  finalize_kernel<<<1, 256, 0, stream>>>(gstats, gn_bias, w_out, b_out, murs,
                                         bias2);
  // normalize + cast to bf16
  norm_cast_kernel<<<(32768 * 512 / 4) / 256, 256, 0, stream>>>(oa, murs,
                                                                gn_scale, A2);
  // final GEMM: (32768x512)@(512x256) + bias2 -> fp32 out
  gemm_bt<float><<<dim3(32768 / 128, 256 / 128), 256, 0, stream>>>(
      A2, woutT, out, 32768, 512, 256, bias2);
}

// Round 4
// 396.060 us; speedup vs baseline: 1.8119x; 1.1059x over previous
//
#include <hip/hip_runtime.h>

// LinearAttention (fp32 in/out, bf16 internal MFMA):
// x(8,64,64,256) f32, w_qkv(256,1536) f32, gn_scale/bias(512) f32,
// w_out(512,256) f32, b_out(256) f32 -> out(8,64,64,256) f32
// B=8, N=4096 tokens/batch, HEADS=8, DH=64, HID=512, DIM=256.
//
// GN folded into final GEMM: out = rs*(oa @ (gs.*w_out)) - rs*mu*gw1 + bias2
//   gw1[c] = sum_f gs[f]*w_out[f,c];  bias2[c] = sum_f gnb[f]*w_out[f,c]+bout[c]

typedef unsigned short ushort_t;
typedef __attribute__((ext_vector_type(8))) short short8;
typedef __attribute__((ext_vector_type(4))) float floatx4;

__device__ __forceinline__ float b2f(ushort_t u) {
  unsigned int i = ((unsigned int)u) << 16;
  float f;
  __builtin_memcpy(&f, &i, 4);
  return f;
}
__device__ __forceinline__ ushort_t f2b(float f) {
  unsigned int i;
  __builtin_memcpy(&i, &f, 4);
  unsigned int r = (i + 0x7FFFu + ((i >> 16) & 1u)) >> 16;
  return (ushort_t)r;
}

// async 16B global->LDS copy (LDS dest must be wave-uniform-base + lane*16)
__device__ __forceinline__ void load_lds16(const ushort_t* g, ushort_t* l) {
  __builtin_amdgcn_global_load_lds(
      (const __attribute__((address_space(1))) unsigned int*)g,
      (__attribute__((address_space(3))) unsigned int*)l, 16, 0, 0);
}

// ---------------------------------------------------------------------------
// Cast fp32 -> bf16, contiguous. 4 elements/thread.
// ---------------------------------------------------------------------------
__global__ __launch_bounds__(256) void cast_f32_bf16(
    const float* __restrict__ in, ushort_t* __restrict__ out) {
  long i = ((long)blockIdx.x * 256 + threadIdx.x) * 4;
  float4 v = *(const float4*)(in + i);
  ushort4 o;
  o.x = f2b(v.x);
  o.y = f2b(v.y);
  o.z = f2b(v.z);
  o.w = f2b(v.w);
  *(ushort4*)(out + i) = o;
}

// ---------------------------------------------------------------------------
// Transpose fp32 R x C -> bf16 C x R, optional per-row scale[r]. R,C mult 32.
// ---------------------------------------------------------------------------
__global__ __launch_bounds__(256) void transpose_f32_bf16(
    const float* __restrict__ in, ushort_t* __restrict__ out, int R, int C,
    const float* __restrict__ scale) {
  __shared__ ushort_t t[32][33];
  int c0 = blockIdx.x * 32, r0 = blockIdx.y * 32;
  int tx = threadIdx.x & 31, ty = threadIdx.x >> 5;  // ty 0..7
  for (int i = 0; i < 32; i += 8) {
    float s = scale ? scale[r0 + ty + i] : 1.0f;
    t[ty + i][tx] = f2b(in[(long)(r0 + ty + i) * C + c0 + tx] * s);
  }
  __syncthreads();
  for (int i = 0; i < 32; i += 8)
    out[(long)(c0 + ty + i) * R + r0 + tx] = t[tx][ty + i];
}

// ---------------------------------------------------------------------------
// Precompute gw1[c] = sum_f gs[f]*wout[f,c]; bias2[c] = sum gnb[f]*wout[f,c]
// + bout[c]. Grid 4 x 64 threads.
// ---------------------------------------------------------------------------
__global__ __launch_bounds__(64) void prep_gw_kernel(
    const float* __restrict__ gn_scale, const float* __restrict__ gn_bias,
    const float* __restrict__ w_out, const float* __restrict__ b_out,
    float* __restrict__ gw1, float* __restrict__ bias2) {
  int c = blockIdx.x * 64 + threadIdx.x;
  float g1 = 0.f, b2 = 0.f;
  for (int f = 0; f < 512; ++f) {
    float w = w_out[f * 256 + c];
    g1 += gn_scale[f] * w;
    b2 += gn_bias[f] * w;
  }
  gw1[c] = g1;
  bias2[c] = b2 + b_out[c];
}

// ---------------------------------------------------------------------------
// MFMA GEMM: C[M,F] = A[M,K] @ Bt[F,K]^T  (bf16 in, bf16 out, fp32 acc)
// Block = 256 thr = 4 waves in 2x2; wave does 64x64 via 4x4 mfma 16x16x32.
// Staging via global_load_lds width-16 (wave-uniform base + lane*16).
// ---------------------------------------------------------------------------
__global__ __launch_bounds__(256) void gemm_bt(
    const ushort_t* __restrict__ A, const ushort_t* __restrict__ Bt,
    ushort_t* __restrict__ C, int M, int K, int F) {
  __shared__ __align__(16) ushort_t As[128][32];
  __shared__ __align__(16) ushort_t Bs[128][32];
  int tid = threadIdx.x;
  long m0 = (long)blockIdx.x * 128;
  long f0 = (long)blockIdx.y * 128;
  int wv = tid >> 6, lane = tid & 63;
  int wm = wv & 1, wf = wv >> 1;
  int l15 = lane & 15, quad = lane >> 4;

  floatx4 acc[4][4];
  floatx4 zero = {0.f, 0.f, 0.f, 0.f};
  for (int i = 0; i < 4; i++)
    for (int j = 0; j < 4; j++) acc[i][j] = zero;

  for (int k0 = 0; k0 < K; k0 += 32) {
    __syncthreads();
#pragma unroll
    for (int r = 0; r < 2; ++r) {
      int chunk = r * 256 + tid;  // 0..511
      int row = chunk >> 2;       // 0..127
      int kc = chunk & 3;         // 0..3 (8 bf16 each)
      load_lds16(A + (m0 + row) * (long)K + k0 + kc * 8, &As[row][kc * 8]);
      load_lds16(Bt + (f0 + row) * (long)K + k0 + kc * 8, &Bs[row][kc * 8]);
    }
    __syncthreads();
    short8 af[4], bfr[4];
#pragma unroll
    for (int mt = 0; mt < 4; mt++)
      af[mt] = *(const short8*)(&As[wm * 64 + mt * 16 + l15][quad * 8]);
#pragma unroll
    for (int ft = 0; ft < 4; ft++)
      bfr[ft] = *(const short8*)(&Bs[wf * 64 + ft * 16 + l15][quad * 8]);
#pragma unroll
    for (int mt = 0; mt < 4; mt++)
#pragma unroll
      for (int ft = 0; ft < 4; ft++)
        acc[mt][ft] = __builtin_amdgcn_mfma_f32_16x16x32_bf16(
            af[mt], bfr[ft], acc[mt][ft], 0, 0, 0);
  }

  // epilogue: D[row = quad*4 + r][col = l15] within each 16x16 tile
#pragma unroll
  for (int mt = 0; mt < 4; mt++)
#pragma unroll
    for (int ft = 0; ft < 4; ft++) {
      long col = f0 + wf * 64 + ft * 16 + l15;
#pragma unroll
      for (int r = 0; r < 4; r++) {
        long row = m0 + wm * 64 + mt * 16 + quad * 4 + r;
        C[row * F + col] = f2b(acc[mt][ft][r]);
      }
    }
}

// ---------------------------------------------------------------------------
// Final MFMA GEMM with folded-GN epilogue (fp32 out):
// out[row,col] = rs_b*acc + bias2[col] - rs_b*mu_b*gw1[col],  b = row>>12.
// ---------------------------------------------------------------------------
__global__ __launch_bounds__(256) void gemm_final(
    const ushort_t* __restrict__ A, const ushort_t* __restrict__ Bt,
    float* __restrict__ C, int M, int K, int F,
    const float* __restrict__ murs, const float* __restrict__ gw1,
    const float* __restrict__ bias2) {
  __shared__ __align__(16) ushort_t As[128][32];
  __shared__ __align__(16) ushort_t Bs[128][32];
  int tid = threadIdx.x;
  long m0 = (long)blockIdx.x * 128;
  long f0 = (long)blockIdx.y * 128;
  int wv = tid >> 6, lane = tid & 63;
  int wm = wv & 1, wf = wv >> 1;
  int l15 = lane & 15, quad = lane >> 4;

  floatx4 acc[4][4];
  floatx4 zero = {0.f, 0.f, 0.f, 0.f};
  for (int i = 0; i < 4; i++)
    for (int j = 0; j < 4; j++) acc[i][j] = zero;

  for (int k0 = 0; k0 < K; k0 += 32) {
    __syncthreads();
#pragma unroll
    for (int r = 0; r < 2; ++r) {
      int chunk = r * 256 + tid;
      int row = chunk >> 2;
      int kc = chunk & 3;
      load_lds16(A + (m0 + row) * (long)K + k0 + kc * 8, &As[row][kc * 8]);
      load_lds16(Bt + (f0 + row) * (long)K + k0 + kc * 8, &Bs[row][kc * 8]);
    }
    __syncthreads();
    short8 af[4], bfr[4];
#pragma unroll
    for (int mt = 0; mt < 4; mt++)
      af[mt] = *(const short8*)(&As[wm * 64 + mt * 16 + l15][quad * 8]);
#pragma unroll
    for (int ft = 0; ft < 4; ft++)
      bfr[ft] = *(const short8*)(&Bs[wf * 64 + ft * 16 + l15][quad * 8]);
#pragma unroll
    for (int mt = 0; mt < 4; mt++)
#pragma unroll
      for (int ft = 0; ft < 4; ft++)
        acc[mt][ft] = __builtin_amdgcn_mfma_f32_16x16x32_bf16(
            af[mt], bfr[ft], acc[mt][ft], 0, 0, 0);
  }

  int b = (int)(m0 >> 12);  // 4096 rows per batch
  float mu = murs[b * 2], rs = murs[b * 2 + 1];
#pragma unroll
  for (int mt = 0; mt < 4; mt++)
#pragma unroll
    for (int ft = 0; ft < 4; ft++) {
      long col = f0 + wf * 64 + ft * 16 + l15;
      float c1 = bias2[col] - rs * mu * gw1[col];
#pragma unroll
      for (int r = 0; r < 4; r++) {
        long row = m0 + wm * 64 + mt * 16 + quad * 4 + r;
        C[row * F + col] = rs * acc[mt][ft][r] + c1;
      }
    }
}

// ---------------------------------------------------------------------------
// k softmax partial stats. Grid (64 bh, 16 chunks of 256 tokens), block 256.
// ---------------------------------------------------------------------------
__global__ __launch_bounds__(256) void kpart_kernel(
    const ushort_t* __restrict__ qkv, float* __restrict__ kpM,
    float* __restrict__ kpS) {
  int bh = blockIdx.x, chunk = blockIdx.y;
  int b = bh >> 3, h = bh & 7;
  int wv = threadIdx.x >> 6, lane = threadIdx.x & 63;
  const ushort_t* base = qkv +
      ((long)b * 4096 + chunk * 256 + wv * 64) * 1536 + 512 + h * 64 + lane;
  float m = -1e30f, s = 0.f;
  for (int i = 0; i < 64; ++i) {
    float v = b2f(base[(long)i * 1536]);
    if (v > m) {
      s = s * __expf(m - v) + 1.0f;
      m = v;
    } else {
      s += __expf(v - m);
    }
  }
  __shared__ float sm[4][64], ss[4][64];
  sm[wv][lane] = m;
  ss[wv][lane] = s;
  __syncthreads();
  if (wv == 0) {
    float M = sm[0][lane], S = ss[0][lane];
    for (int w2 = 1; w2 < 4; w2++) {
      float m2 = sm[w2][lane], s2 = ss[w2][lane];
      float nm = fmaxf(M, m2);
      S = S * __expf(M - nm) + s2 * __expf(m2 - nm);
      M = nm;
    }
    int idx = (bh * 16 + chunk) * 64 + lane;
    kpM[idx] = M;
    kpS[idx] = S;
  }
}

// ---------------------------------------------------------------------------
// Combine 16 partial (m,s) per (bh,d) -> kmax, kinv. Grid 64, block 64.
// ---------------------------------------------------------------------------
__global__ __launch_bounds__(64) void kcombine_kernel(
    const float* __restrict__ kpM, const float* __restrict__ kpS,
    float* __restrict__ kmax, float* __restrict__ kinv) {
  int bh = blockIdx.x, lane = threadIdx.x;
  float M = -1e30f, S = 0.f;
  for (int c = 0; c < 16; ++c) {
    float m2 = kpM[(bh * 16 + c) * 64 + lane];
    float s2 = kpS[(bh * 16 + c) * 64 + lane];
    float nm = fmaxf(M, m2);
    S = S * __expf(M - nm) + s2 * __expf(m2 - nm);
    M = nm;
  }
  kmax[bh * 64 + lane] = M;
  kinv[bh * 64 + lane] = 1.0f / S;
}

// ---------------------------------------------------------------------------
// ctxT[bh][e][d] += sum_n exp(k[d,n]-kmax[d])*kinv[d] * v[e,n]   (transposed!)
// Grid (64 bh, 16 n-chunks of 256). fp32 atomic accumulate into zeroed ctxT.
// ---------------------------------------------------------------------------
__global__ __launch_bounds__(256) void ctx_kernel(
    const ushort_t* __restrict__ qkv, const float* __restrict__ kmax,
    const float* __restrict__ kinv, float* __restrict__ ctxT) {
  int bh = blockIdx.x;
  int chunk = blockIdx.y;
  int b = bh >> 3, h = bh & 7;
  int tid = threadIdx.x;
  __shared__ float pk[64][65];
  __shared__ float pv[64][65];
  int dl = tid & 63;  // loading role: d (and e) index
  int nl = tid >> 6;  // 0..3
  float km = kmax[bh * 64 + dl], ki = kinv[bh * 64 + dl];
  int td = tid & 15, te = tid >> 4;
  float acc[4][4] = {};
  long rowbase = (long)b * 4096 + chunk * 256;
  for (int t = 0; t < 4; ++t) {  // 4 tiles of 64 tokens
    __syncthreads();
    for (int r = 0; r < 16; ++r) {
      int n = t * 64 + r * 4 + nl;
      const ushort_t* p = qkv + (rowbase + n) * 1536 + h * 64 + dl;
      pk[dl][r * 4 + nl] = __expf(b2f(p[512]) - km) * ki;
      pv[dl][r * 4 + nl] = b2f(p[1024]);
    }
    __syncthreads();
    for (int n = 0; n < 64; ++n) {
      float kd[4], ve[4];
#pragma unroll
      for (int i = 0; i < 4; i++) kd[i] = pk[td * 4 + i][n];
#pragma unroll
      for (int j = 0; j < 4; j++) ve[j] = pv[te * 4 + j][n];
#pragma unroll
      for (int i = 0; i < 4; i++)
#pragma unroll
        for (int j = 0; j < 4; j++) acc[i][j] += kd[i] * ve[j];
    }
  }
  float* cbase = ctxT + (long)bh * 4096;
#pragma unroll
  for (int i = 0; i < 4; i++)
#pragma unroll
    for (int j = 0; j < 4; j++)  // ctxT[e][d] = ctx[d][e]
      atomicAdd(&cbase[(te * 4 + j) * 64 + td * 4 + i], acc[i][j]);
}

// ---------------------------------------------------------------------------
// Fused q-softmax + P@ctxT MFMA. Grid (64 bh, 16 chunks of 256 tokens).
// A2[n, h*64+e] (bf16, un-normalized attention out) + GN stats atomics.
// ---------------------------------------------------------------------------
__global__ __launch_bounds__(256) void qp_gemm_kernel(
    const ushort_t* __restrict__ qkv, const float* __restrict__ ctxT,
    ushort_t* __restrict__ A2, float* __restrict__ gstats) {
  int bh = blockIdx.x, chunk = blockIdx.y;
  int b = bh >> 3, h = bh & 7;
  int tid = threadIdx.x, wv = tid >> 6, lane = tid & 63;
  int l15 = lane & 15, quad = lane >> 4;
  __shared__ __align__(16) ushort_t As[256][72];  // P[token][d] bf16
  __shared__ __align__(16) ushort_t Bs[64][72];   // ctxT[e][d] bf16

  // stage ctxT (64x64 f32) -> Bs bf16: thread covers 16 floats
  {
    int e = tid >> 2, c4 = (tid & 3) * 16;
    const float* src = ctxT + (long)bh * 4096 + e * 64 + c4;
#pragma unroll
    for (int j = 0; j < 16; j += 4) {
      float4 v = *(const float4*)(src + j);
      Bs[e][c4 + j + 0] = f2b(v.x);
      Bs[e][c4 + j + 1] = f2b(v.y);
      Bs[e][c4 + j + 2] = f2b(v.z);
      Bs[e][c4 + j + 3] = f2b(v.w);
    }
  }

  // q softmax: wave wv handles tokens wv*64..+63, lane = d (coalesced 128B)
  long rowbase = (long)b * 4096 + chunk * 256;
  for (int t = 0; t < 64; ++t) {
    int tok = wv * 64 + t;
    float qv = b2f(qkv[(rowbase + tok) * 1536 + h * 64 + lane]);
    float m = qv;
    for (int o = 32; o > 0; o >>= 1) m = fmaxf(m, __shfl_xor(m, o));
    float e = __expf(qv - m);
    float s = e;
    for (int o = 32; o > 0; o >>= 1) s += __shfl_xor(s, o);
    As[tok][lane] = f2b(e / s * 0.125f);  // * DH^-0.5
  }
  __syncthreads();

  // MFMA: wave wv computes tokens wv*64..+63 x e 0..63 (4x4 of 16x16, K=64)
  floatx4 acc[4][4];
  floatx4 zero = {0.f, 0.f, 0.f, 0.f};
  for (int i = 0; i < 4; i++)
    for (int j = 0; j < 4; j++) acc[i][j] = zero;
#pragma unroll
  for (int k0 = 0; k0 < 64; k0 += 32) {
    short8 af[4], bfr[4];
#pragma unroll
    for (int mt = 0; mt < 4; mt++)
      af[mt] = *(const short8*)(&As[wv * 64 + mt * 16 + l15][k0 + quad * 8]);
#pragma unroll
    for (int ft = 0; ft < 4; ft++)
      bfr[ft] = *(const short8*)(&Bs[ft * 16 + l15][k0 + quad * 8]);
#pragma unroll
    for (int mt = 0; mt < 4; mt++)
#pragma unroll
      for (int ft = 0; ft < 4; ft++)
        acc[mt][ft] = __builtin_amdgcn_mfma_f32_16x16x32_bf16(
            af[mt], bfr[ft], acc[mt][ft], 0, 0, 0);
  }

  // epilogue: bf16 store + GN stats
  float lsum = 0.f, lss = 0.f;
#pragma unroll
  for (int mt = 0; mt < 4; mt++)
#pragma unroll
    for (int ft = 0; ft < 4; ft++) {
      int col = h * 64 + ft * 16 + l15;
#pragma unroll
      for (int r = 0; r < 4; r++) {
        long row = rowbase + wv * 64 + mt * 16 + quad * 4 + r;
        float v = acc[mt][ft][r];
        A2[row * 512 + col] = f2b(v);
        lsum += v;
        lss += v * v;
      }
    }
  for (int o = 32; o > 0; o >>= 1) {
    lsum += __shfl_xor(lsum, o);
    lss += __shfl_xor(lss, o);
  }
  __shared__ float red[4][2];
  if (lane == 0) {
    red[wv][0] = lsum;
    red[wv][1] = lss;
  }
  __syncthreads();
  if (tid == 0) {
    float a = 0.f, c = 0.f;
    for (int w2 = 0; w2 < 4; w2++) {
      a += red[w2][0];
      c += red[w2][1];
    }
    atomicAdd(&gstats[b * 2], a);
    atomicAdd(&gstats[b * 2 + 1], c);
  }
}

// ---------------------------------------------------------------------------
// mu/rsqrt per batch from gstats. 1 block, 64 threads.
// ---------------------------------------------------------------------------
__global__ __launch_bounds__(64) void finalize_murs(
    const float* __restrict__ gstats, float* __restrict__ murs) {
  int tid = threadIdx.x;
  if (tid < 8) {
    float cnt = 4096.f * 512.f;
    float mu = gstats[tid * 2] / cnt;
    float var = gstats[tid * 2 + 1] / cnt - mu * mu;
    murs[tid * 2] = mu;
    murs[tid * 2 + 1] = rsqrtf(var + 1e-5f);
  }
}

// ---------------------------------------------------------------------------
extern "C" void kernel_launch(void* const* d_in, const int* in_sizes, int n_in,
                              void* d_out, int out_size, void* d_ws,
                              size_t ws_size, hipStream_t stream) {
  const float* x = (const float*)d_in[0];         // 8*64*64*256 f32
  const float* w_qkv = (const float*)d_in[1];     // 256*1536 f32
  const float* gn_scale = (const float*)d_in[2];  // 512 f32
  const float* gn_bias = (const float*)d_in[3];   // 512 f32
  const float* w_out = (const float*)d_in[4];     // 512*256 f32
  const float* b_out = (const float*)d_in[5];     // 256 f32
  float* out = (float*)d_out;                     // 8*64*64*256 f32

  char* w = (char*)d_ws;
  ushort_t* qkv = (ushort_t*)(w + 0);            // 100663296 B (32768x1536 bf16)
  ushort_t* A2 = (ushort_t*)(w + 100663296);     // 33554432 B (32768x512 bf16)
  ushort_t* xb = (ushort_t*)(w + 167772160);     // 16777216 B (32768x256 bf16)
  ushort_t* wqkvT = (ushort_t*)(w + 184549376);  // 786432 B (1536x256 bf16)
  ushort_t* w2T = (ushort_t*)(w + 185335808);    // 262144 B (256x512 bf16)
  float* kmax = (float*)(w + 185597952);         // 16384 B
  float* kinv = (float*)(w + 185614336);         // 16384 B
  float* ctxT = (float*)(w + 185630720);         // 1048576 B (64*64*64 f32)
  float* gstats = (float*)(w + 186679296);       // 64 B (8 x {sum,ss})
  float* murs = (float*)(w + 186679360);         // 64 B
  float* bias2 = (float*)(w + 186679424);        // 1024 B
  float* gw1 = (float*)(w + 186680448);          // 1024 B
  float* kpM = (float*)(w + 186681472);          // 262144 B
  float* kpS = (float*)(w + 186943616);          // 262144 B

  // zero ctxT + gstats (contiguous)
  hipMemsetAsync(ctxT, 0, 1048576 + 64, stream);

  // cast x -> bf16
  cast_f32_bf16<<<8388608 / 4 / 256, 256, 0, stream>>>(x, xb);
  // transposes+cast: w_qkv -> (1536x256); w_out -> gs-scaled (256x512)
  transpose_f32_bf16<<<dim3(1536 / 32, 256 / 32), 256, 0, stream>>>(
      w_qkv, wqkvT, 256, 1536, nullptr);
  transpose_f32_bf16<<<dim3(256 / 32, 512 / 32), 256, 0, stream>>>(
      w_out, w2T, 512, 256, gn_scale);
  // gw1 + bias2 precompute
  prep_gw_kernel<<<4, 64, 0, stream>>>(gn_scale, gn_bias, w_out, b_out, gw1,
                                       bias2);
  // QKV GEMM: (32768x256)@(256x1536) -> bf16 qkv
  gemm_bt<<<dim3(32768 / 128, 1536 / 128), 256, 0, stream>>>(
      xb, wqkvT, qkv, 32768, 256, 1536);
  // k softmax stats: two-level reduction
  kpart_kernel<<<dim3(64, 16), 256, 0, stream>>>(qkv, kpM, kpS);
  kcombine_kernel<<<64, 64, 0, stream>>>(kpM, kpS, kmax, kinv);
  // context (transposed layout)
  ctx_kernel<<<dim3(64, 16), 256, 0, stream>>>(qkv, kmax, kinv, ctxT);
  // fused q-softmax + P@ctxT -> A2 (bf16) + GN stats
  qp_gemm_kernel<<<dim3(64, 16), 256, 0, stream>>>(qkv, ctxT, A2, gstats);
  // mu / rsqrt per batch
  finalize_murs<<<1, 64, 0, stream>>>(gstats, murs);
  // final GEMM with folded GN epilogue: (32768x512)@(512x256) -> fp32 out
  gemm_final<<<dim3(32768 / 128, 256 / 128), 256, 0, stream>>>(
      A2, w2T, out, 32768, 512, 256, murs, gw1, bias2);
}

// Round 5
// 301.325 us; speedup vs baseline: 2.3815x; 1.3144x over previous
//
#include <hip/hip_runtime.h>

// LinearAttention (fp32 in/out, bf16 internal MFMA):
// x(8,64,64,256) f32, w_qkv(256,1536) f32, gn_scale/bias(512) f32,
// w_out(512,256) f32, b_out(256) f32 -> out(8,64,64,256) f32
// B=8, N=4096 tokens/batch, HEADS=8, DH=64, HID=512, DIM=256.
//
// Softmaxes computed WITHOUT max subtraction (|q|,|k| <~ 6, exp fp32-safe).
// k-norm folded: ctxT holds raw sums; qp scales by 1/ksum[d] at staging.
// q-norm folded: MFMA on raw exp(q); epilogue row-scale by 0.125/s_n.
// GN folded into final GEMM: out = rs*(oa @ (gs.*w_out)) - rs*mu*gw1 + bias2

typedef unsigned short ushort_t;
typedef __attribute__((ext_vector_type(8))) short short8;
typedef __attribute__((ext_vector_type(4))) float floatx4;

__device__ __forceinline__ float b2f(ushort_t u) {
  unsigned int i = ((unsigned int)u) << 16;
  float f;
  __builtin_memcpy(&f, &i, 4);
  return f;
}
__device__ __forceinline__ ushort_t f2b(float f) {
  unsigned int i;
  __builtin_memcpy(&i, &f, 4);
  unsigned int r = (i + 0x7FFFu + ((i >> 16) & 1u)) >> 16;
  return (ushort_t)r;
}

// async 16B global->LDS copy (HW dest = wave-uniform base + lane*16)
__device__ __forceinline__ void load_lds16(const ushort_t* g, ushort_t* l) {
  __builtin_amdgcn_global_load_lds(
      (const __attribute__((address_space(1))) unsigned int*)g,
      (__attribute__((address_space(3))) unsigned int*)l, 16, 0, 0);
}

// ---------------------------------------------------------------------------
// Cast fp32 -> bf16, contiguous. 4 elements/thread.
// ---------------------------------------------------------------------------
__global__ __launch_bounds__(256) void cast_f32_bf16(
    const float* __restrict__ in, ushort_t* __restrict__ out) {
  long i = ((long)blockIdx.x * 256 + threadIdx.x) * 4;
  float4 v = *(const float4*)(in + i);
  ushort4 o;
  o.x = f2b(v.x);
  o.y = f2b(v.y);
  o.z = f2b(v.z);
  o.w = f2b(v.w);
  *(ushort4*)(out + i) = o;
}

// ---------------------------------------------------------------------------
// Transpose fp32 R x C -> bf16 C x R, optional per-row scale[r]. R,C mult 32.
// ---------------------------------------------------------------------------
__global__ __launch_bounds__(256) void transpose_f32_bf16(
    const float* __restrict__ in, ushort_t* __restrict__ out, int R, int C,
    const float* __restrict__ scale) {
  __shared__ ushort_t t[32][33];
  int c0 = blockIdx.x * 32, r0 = blockIdx.y * 32;
  int tx = threadIdx.x & 31, ty = threadIdx.x >> 5;  // ty 0..7
  for (int i = 0; i < 32; i += 8) {
    float s = scale ? scale[r0 + ty + i] : 1.0f;
    t[ty + i][tx] = f2b(in[(long)(r0 + ty + i) * C + c0 + tx] * s);
  }
  __syncthreads();
  for (int i = 0; i < 32; i += 8)
    out[(long)(c0 + ty + i) * R + r0 + tx] = t[tx][ty + i];
}

// ---------------------------------------------------------------------------
// Precompute gw1[c] = sum_f gs[f]*wout[f,c]; bias2[c] = sum gnb[f]*wout[f,c]
// + bout[c]. Grid 4 x 64 threads.
// ---------------------------------------------------------------------------
__global__ __launch_bounds__(64) void prep_gw_kernel(
    const float* __restrict__ gn_scale, const float* __restrict__ gn_bias,
    const float* __restrict__ w_out, const float* __restrict__ b_out,
    float* __restrict__ gw1, float* __restrict__ bias2) {
  int c = blockIdx.x * 64 + threadIdx.x;
  float g1 = 0.f, b2 = 0.f;
  for (int f = 0; f < 512; ++f) {
    float w = w_out[f * 256 + c];
    g1 += gn_scale[f] * w;
    b2 += gn_bias[f] * w;
  }
  gw1[c] = g1;
  bias2[c] = b2 + b_out[c];
}

// ---------------------------------------------------------------------------
// MFMA GEMM: C[M,F] = A[M,K] @ Bt[F,K]^T  (bf16 in, bf16 out, fp32 acc)
// Block = 256 thr = 4 waves in 2x2; wave does 64x64 via 4x4 mfma 16x16x32.
// ---------------------------------------------------------------------------
__global__ __launch_bounds__(256) void gemm_bt(
    const ushort_t* __restrict__ A, const ushort_t* __restrict__ Bt,
    ushort_t* __restrict__ C, int M, int K, int F) {
  __shared__ __align__(16) ushort_t As[128][32];
  __shared__ __align__(16) ushort_t Bs[128][32];
  int tid = threadIdx.x;
  long m0 = (long)blockIdx.x * 128;
  long f0 = (long)blockIdx.y * 128;
  int wv = tid >> 6, lane = tid & 63;
  int wm = wv & 1, wf = wv >> 1;
  int l15 = lane & 15, quad = lane >> 4;

  floatx4 acc[4][4];
  floatx4 zero = {0.f, 0.f, 0.f, 0.f};
  for (int i = 0; i < 4; i++)
    for (int j = 0; j < 4; j++) acc[i][j] = zero;

  for (int k0 = 0; k0 < K; k0 += 32) {
    __syncthreads();
#pragma unroll
    for (int r = 0; r < 2; ++r) {
      int chunk = r * 256 + tid;  // 0..511
      int row = chunk >> 2;       // 0..127
      int kc = chunk & 3;         // 0..3 (8 bf16 each)
      load_lds16(A + (m0 + row) * (long)K + k0 + kc * 8, &As[row][kc * 8]);
      load_lds16(Bt + (f0 + row) * (long)K + k0 + kc * 8, &Bs[row][kc * 8]);
    }
    __syncthreads();
    short8 af[4], bfr[4];
#pragma unroll
    for (int mt = 0; mt < 4; mt++)
      af[mt] = *(const short8*)(&As[wm * 64 + mt * 16 + l15][quad * 8]);
#pragma unroll
    for (int ft = 0; ft < 4; ft++)
      bfr[ft] = *(const short8*)(&Bs[wf * 64 + ft * 16 + l15][quad * 8]);
#pragma unroll
    for (int mt = 0; mt < 4; mt++)
#pragma unroll
      for (int ft = 0; ft < 4; ft++)
        acc[mt][ft] = __builtin_amdgcn_mfma_f32_16x16x32_bf16(
            af[mt], bfr[ft], acc[mt][ft], 0, 0, 0);
  }

#pragma unroll
  for (int mt = 0; mt < 4; mt++)
#pragma unroll
    for (int ft = 0; ft < 4; ft++) {
      long col = f0 + wf * 64 + ft * 16 + l15;
#pragma unroll
      for (int r = 0; r < 4; r++) {
        long row = m0 + wm * 64 + mt * 16 + quad * 4 + r;
        C[row * F + col] = f2b(acc[mt][ft][r]);
      }
    }
}

// ---------------------------------------------------------------------------
// Final MFMA GEMM with folded-GN epilogue (fp32 out):
// out[row,col] = rs_b*acc + bias2[col] - rs_b*mu_b*gw1[col],  b = row>>12.
// ---------------------------------------------------------------------------
__global__ __launch_bounds__(256) void gemm_final(
    const ushort_t* __restrict__ A, const ushort_t* __restrict__ Bt,
    float* __restrict__ C, int M, int K, int F,
    const float* __restrict__ murs, const float* __restrict__ gw1,
    const float* __restrict__ bias2) {
  __shared__ __align__(16) ushort_t As[128][32];
  __shared__ __align__(16) ushort_t Bs[128][32];
  int tid = threadIdx.x;
  long m0 = (long)blockIdx.x * 128;
  long f0 = (long)blockIdx.y * 128;
  int wv = tid >> 6, lane = tid & 63;
  int wm = wv & 1, wf = wv >> 1;
  int l15 = lane & 15, quad = lane >> 4;

  floatx4 acc[4][4];
  floatx4 zero = {0.f, 0.f, 0.f, 0.f};
  for (int i = 0; i < 4; i++)
    for (int j = 0; j < 4; j++) acc[i][j] = zero;

  for (int k0 = 0; k0 < K; k0 += 32) {
    __syncthreads();
#pragma unroll
    for (int r = 0; r < 2; ++r) {
      int chunk = r * 256 + tid;
      int row = chunk >> 2;
      int kc = chunk & 3;
      load_lds16(A + (m0 + row) * (long)K + k0 + kc * 8, &As[row][kc * 8]);
      load_lds16(Bt + (f0 + row) * (long)K + k0 + kc * 8, &Bs[row][kc * 8]);
    }
    __syncthreads();
    short8 af[4], bfr[4];
#pragma unroll
    for (int mt = 0; mt < 4; mt++)
      af[mt] = *(const short8*)(&As[wm * 64 + mt * 16 + l15][quad * 8]);
#pragma unroll
    for (int ft = 0; ft < 4; ft++)
      bfr[ft] = *(const short8*)(&Bs[wf * 64 + ft * 16 + l15][quad * 8]);
#pragma unroll
    for (int mt = 0; mt < 4; mt++)
#pragma unroll
      for (int ft = 0; ft < 4; ft++)
        acc[mt][ft] = __builtin_amdgcn_mfma_f32_16x16x32_bf16(
            af[mt], bfr[ft], acc[mt][ft], 0, 0, 0);
  }

  int b = (int)(m0 >> 12);  // 4096 rows per batch
  float mu = murs[b * 2], rs = murs[b * 2 + 1];
#pragma unroll
  for (int mt = 0; mt < 4; mt++)
#pragma unroll
    for (int ft = 0; ft < 4; ft++) {
      long col = f0 + wf * 64 + ft * 16 + l15;
      float c1 = bias2[col] - rs * mu * gw1[col];
#pragma unroll
      for (int r = 0; r < 4; r++) {
        long row = m0 + wm * 64 + mt * 16 + quad * 4 + r;
        C[row * F + col] = rs * acc[mt][ft][r] + c1;
      }
    }
}

// ---------------------------------------------------------------------------
// ctxT[bh][e][d] += sum_n exp(k[d,n]) * v[e,n]   (raw, un-normalized)
// Also atomically accumulates ksum[bh][d] = sum_n exp(k[d,n]).
// Grid (64 bh, 16 n-chunks of 256). fp32 atomics into zeroed buffers.
// ---------------------------------------------------------------------------
__global__ __launch_bounds__(256) void ctx_kernel(
    const ushort_t* __restrict__ qkv, float* __restrict__ ctxT,
    float* __restrict__ ksum) {
  int bh = blockIdx.x;
  int chunk = blockIdx.y;
  int b = bh >> 3, h = bh & 7;
  int tid = threadIdx.x;
  __shared__ float pk[64][65];
  __shared__ float pv[64][65];
  __shared__ float es[4][64];
  int dl = tid & 63;  // loading role: d (and e) index
  int nl = tid >> 6;  // 0..3
  int td = tid & 15, te = tid >> 4;
  float acc[4][4] = {};
  float esum = 0.f;
  long rowbase = (long)b * 4096 + chunk * 256;
  for (int t = 0; t < 4; ++t) {  // 4 tiles of 64 tokens
    __syncthreads();
    for (int r = 0; r < 16; ++r) {
      int n = t * 64 + r * 4 + nl;
      const ushort_t* p = qkv + (rowbase + n) * 1536 + h * 64 + dl;
      float e = __expf(b2f(p[512]));
      pk[dl][r * 4 + nl] = e;
      esum += e;
      pv[dl][r * 4 + nl] = b2f(p[1024]);
    }
    __syncthreads();
    for (int n = 0; n < 64; ++n) {
      float kd[4], ve[4];
#pragma unroll
      for (int i = 0; i < 4; i++) kd[i] = pk[td * 4 + i][n];
#pragma unroll
      for (int j = 0; j < 4; j++) ve[j] = pv[te * 4 + j][n];
#pragma unroll
      for (int i = 0; i < 4; i++)
#pragma unroll
        for (int j = 0; j < 4; j++) acc[i][j] += kd[i] * ve[j];
    }
  }
  // ksum reduction over nl
  es[nl][dl] = esum;
  __syncthreads();
  if (nl == 0)
    atomicAdd(&ksum[bh * 64 + dl],
              es[0][dl] + es[1][dl] + es[2][dl] + es[3][dl]);
  float* cbase = ctxT + (long)bh * 4096;
#pragma unroll
  for (int i = 0; i < 4; i++)
#pragma unroll
    for (int j = 0; j < 4; j++)  // ctxT[e][d] = ctx[d][e]
      atomicAdd(&cbase[(te * 4 + j) * 64 + td * 4 + i], acc[i][j]);
}

// ---------------------------------------------------------------------------
// Fused q-softmax + P@ctx MFMA, shuffle-free. Grid (64 bh, 16 chunks of 256).
// q-tile staged via global_load_lds into XOR-swizzled LDS (16B chunks,
// slot = chunk ^ (tok&7)); per-thread exp+sum (thread t owns token t);
// MFMA on raw exp; epilogue row-scales by 0.125/s_n. ctx scaled by 1/ksum[d]
// at staging. Writes un-normalized-GN A2 (bf16) + GN stats atomics.
// ---------------------------------------------------------------------------
__global__ __launch_bounds__(256) void qp_gemm_kernel(
    const ushort_t* __restrict__ qkv, const float* __restrict__ ctxT,
    const float* __restrict__ ksum, ushort_t* __restrict__ A2,
    float* __restrict__ gstats) {
  int bh = blockIdx.x, chunk = blockIdx.y;
  int b = bh >> 3, h = bh & 7;
  int tid = threadIdx.x, wv = tid >> 6, lane = tid & 63;
  int l15 = lane & 15, quad = lane >> 4;
  __shared__ __align__(16) ushort_t As[256 * 64];  // swizzled 128B rows
  __shared__ __align__(16) ushort_t Bs[64 * 64];   // swizzled 128B rows
  __shared__ float kv[64];
  __shared__ float rs[256];
  __shared__ float red[4][2];

  long rowbase = (long)b * 4096 + chunk * 256;

  // kinv -> LDS
  if (tid < 64) kv[tid] = 1.0f / ksum[bh * 64 + tid];

  // stage q-tile (256 tok x 64 d) via global_load_lds, swizzled chunks
  {
    int tl = lane >> 3;  // token-in-group 0..7
    int c = lane & 7;    // dest chunk slot
    int j = c ^ tl;      // source chunk (tok&7 == tl)
    const ushort_t* g =
        qkv + (rowbase + wv * 64 + tl) * 1536 + h * 64 + j * 8;
#pragma unroll
    for (int i = 0; i < 8; ++i)
      load_lds16(g + (long)i * 8 * 1536, As + (wv * 64 + i * 8) * 64 + lane * 8);
  }

  // read ctxT tile (64x64 f32) into regs while loads fly
  int be = tid >> 2, d0 = (tid & 3) * 16;
  float4 cv[4];
  {
    const float* src = ctxT + (long)bh * 4096 + be * 64 + d0;
#pragma unroll
    for (int j = 0; j < 4; ++j) cv[j] = *(const float4*)(src + j * 4);
  }
  __syncthreads();  // q-tile + kv visible

  // Bs[e][d] = bf16(ctxT[e][d] * kinv[d]), swizzled
  {
#pragma unroll
    for (int j2 = 0; j2 < 2; ++j2) {
      int chunkd = (d0 >> 3) + j2;
      int slot = chunkd ^ (be & 7);
      short8 o;
#pragma unroll
      for (int u = 0; u < 8; ++u) {
        float f = ((const float*)cv)[j2 * 8 + u] * kv[d0 + j2 * 8 + u];
        o[u] = (short)f2b(f);
      }
      *(short8*)(Bs + be * 64 + slot * 8) = o;
    }
  }

  // per-thread softmax-sum: thread t owns token t; exp in place, sum in reg
  {
    int t7 = tid & 7;
    ushort_t* row = As + tid * 64;
    float s = 0.f;
#pragma unroll
    for (int j = 0; j < 8; ++j) {
      int slot = j ^ t7;
      short8 vq = *(const short8*)(row + slot * 8);
      short8 eo;
#pragma unroll
      for (int u = 0; u < 8; ++u) {
        float e = __expf(b2f((ushort_t)vq[u]));
        s += e;
        eo[u] = (short)f2b(e);
      }
      *(short8*)(row + slot * 8) = eo;
    }
    rs[tid] = 0.125f / s;
  }
  __syncthreads();  // As(exp) + Bs + rs visible

  // MFMA: wave wv -> tokens wv*64..+63 x e 0..63 (4x4 of 16x16, K=64)
  floatx4 acc[4][4];
  floatx4 zero = {0.f, 0.f, 0.f, 0.f};
  for (int i = 0; i < 4; i++)
    for (int j = 0; j < 4; j++) acc[i][j] = zero;
#pragma unroll
  for (int k0 = 0; k0 < 2; ++k0) {
    short8 af[4], bfr[4];
#pragma unroll
    for (int mt = 0; mt < 4; mt++) {
      int row = wv * 64 + mt * 16 + l15;
      int slot = (k0 * 4 + quad) ^ (row & 7);
      af[mt] = *(const short8*)(As + row * 64 + slot * 8);
    }
#pragma unroll
    for (int ft = 0; ft < 4; ft++) {
      int e = ft * 16 + l15;
      int slot = (k0 * 4 + quad) ^ (e & 7);
      bfr[ft] = *(const short8*)(Bs + e * 64 + slot * 8);
    }
#pragma unroll
    for (int mt = 0; mt < 4; mt++)
#pragma unroll
      for (int ft = 0; ft < 4; ft++)
        acc[mt][ft] = __builtin_amdgcn_mfma_f32_16x16x32_bf16(
            af[mt], bfr[ft], acc[mt][ft], 0, 0, 0);
  }

  // epilogue: row-scale by rs, bf16 store, GN stats
  float lsum = 0.f, lss = 0.f;
#pragma unroll
  for (int mt = 0; mt < 4; mt++) {
    float rsv[4];
#pragma unroll
    for (int r = 0; r < 4; r++)
      rsv[r] = rs[wv * 64 + mt * 16 + quad * 4 + r];
#pragma unroll
    for (int ft = 0; ft < 4; ft++) {
      int col = h * 64 + ft * 16 + l15;
#pragma unroll
      for (int r = 0; r < 4; r++) {
        long row = rowbase + wv * 64 + mt * 16 + quad * 4 + r;
        float v = acc[mt][ft][r] * rsv[r];
        A2[row * 512 + col] = f2b(v);
        lsum += v;
        lss += v * v;
      }
    }
  }
  for (int o = 32; o > 0; o >>= 1) {
    lsum += __shfl_xor(lsum, o);
    lss += __shfl_xor(lss, o);
  }
  if (lane == 0) {
    red[wv][0] = lsum;
    red[wv][1] = lss;
  }
  __syncthreads();
  if (tid == 0) {
    float a = 0.f, c = 0.f;
    for (int w2 = 0; w2 < 4; w2++) {
      a += red[w2][0];
      c += red[w2][1];
    }
    atomicAdd(&gstats[b * 2], a);
    atomicAdd(&gstats[b * 2 + 1], c);
  }
}

// ---------------------------------------------------------------------------
// mu/rsqrt per batch from gstats. 1 block, 64 threads.
// ---------------------------------------------------------------------------
__global__ __launch_bounds__(64) void finalize_murs(
    const float* __restrict__ gstats, float* __restrict__ murs) {
  int tid = threadIdx.x;
  if (tid < 8) {
    float cnt = 4096.f * 512.f;
    float mu = gstats[tid * 2] / cnt;
    float var = gstats[tid * 2 + 1] / cnt - mu * mu;
    murs[tid * 2] = mu;
    murs[tid * 2 + 1] = rsqrtf(var + 1e-5f);
  }
}

// ---------------------------------------------------------------------------
extern "C" void kernel_launch(void* const* d_in, const int* in_sizes, int n_in,
                              void* d_out, int out_size, void* d_ws,
                              size_t ws_size, hipStream_t stream) {
  const float* x = (const float*)d_in[0];         // 8*64*64*256 f32
  const float* w_qkv = (const float*)d_in[1];     // 256*1536 f32
  const float* gn_scale = (const float*)d_in[2];  // 512 f32
  const float* gn_bias = (const float*)d_in[3];   // 512 f32
  const float* w_out = (const float*)d_in[4];     // 512*256 f32
  const float* b_out = (const float*)d_in[5];     // 256 f32
  float* out = (float*)d_out;                     // 8*64*64*256 f32

  char* w = (char*)d_ws;
  ushort_t* qkv = (ushort_t*)(w + 0);            // 100663296 B (32768x1536 bf16)
  ushort_t* A2 = (ushort_t*)(w + 100663296);     // 33554432 B (32768x512 bf16)
  ushort_t* xb = (ushort_t*)(w + 167772160);     // 16777216 B (32768x256 bf16)
  ushort_t* wqkvT = (ushort_t*)(w + 184549376);  // 786432 B (1536x256 bf16)
  ushort_t* w2T = (ushort_t*)(w + 185335808);    // 262144 B (256x512 bf16)
  float* ctxT = (float*)(w + 185630720);         // 1048576 B (64*64*64 f32)
  float* gstats = (float*)(w + 186679296);       // 64 B (8 x {sum,ss})
  float* ksum = (float*)(w + 186679360);         // 16384 B (64*64 f32)
  float* murs = (float*)(w + 186695744);         // 64 B
  float* bias2 = (float*)(w + 186695808);        // 1024 B
  float* gw1 = (float*)(w + 186696832);          // 1024 B

  // zero ctxT + gstats + ksum (contiguous)
  hipMemsetAsync(ctxT, 0, 1048576 + 64 + 16384, stream);

  // cast x -> bf16
  cast_f32_bf16<<<8388608 / 4 / 256, 256, 0, stream>>>(x, xb);
  // transposes+cast: w_qkv -> (1536x256); w_out -> gs-scaled (256x512)
  transpose_f32_bf16<<<dim3(1536 / 32, 256 / 32), 256, 0, stream>>>(
      w_qkv, wqkvT, 256, 1536, nullptr);
  transpose_f32_bf16<<<dim3(256 / 32, 512 / 32), 256, 0, stream>>>(
      w_out, w2T, 512, 256, gn_scale);
  // gw1 + bias2 precompute
  prep_gw_kernel<<<4, 64, 0, stream>>>(gn_scale, gn_bias, w_out, b_out, gw1,
                                       bias2);
  // QKV GEMM: (32768x256)@(256x1536) -> bf16 qkv
  gemm_bt<<<dim3(32768 / 128, 1536 / 128), 256, 0, stream>>>(
      xb, wqkvT, qkv, 32768, 256, 1536);
  // context (raw) + k exp-sums
  ctx_kernel<<<dim3(64, 16), 256, 0, stream>>>(qkv, ctxT, ksum);
  // fused q-softmax + P@ctx -> A2 (bf16) + GN stats
  qp_gemm_kernel<<<dim3(64, 16), 256, 0, stream>>>(qkv, ctxT, ksum, A2,
                                                   gstats);
  // mu / rsqrt per batch
  finalize_murs<<<1, 64, 0, stream>>>(gstats, murs);
  // final GEMM with folded GN epilogue: (32768x512)@(512x256) -> fp32 out
  gemm_final<<<dim3(32768 / 128, 256 / 128), 256, 0, stream>>>(
      A2, w2T, out, 32768, 512, 256, murs, gw1, bias2);
}